// Round 7
// baseline (307.496 us; speedup 1.0000x reference)
//
#include <hip/hip_runtime.h>
#include <hip/hip_bf16.h>
#include <cstdint>
#include <cstddef>
#include <cstring>

// Problem constants
#define HDIM 256
#define EDIM 512
#define NB   2
#define NSQ  512
#define NSK  512

typedef _Float16 f16x8 __attribute__((ext_vector_type(8)));
typedef _Float16 h2    __attribute__((ext_vector_type(2)));
typedef __fp16   fp16v2 __attribute__((ext_vector_type(2)));
typedef float    f32x4  __attribute__((ext_vector_type(4)));
typedef float    f32x16 __attribute__((ext_vector_type(16)));

// Workspace layout (ushort elements).
// W2/W3 now in 32x32x16 A-frag layout:
//   frag[t][sc][lane][j8] = W[(sc*16 + (lane>>5)*8 + j)*256 + t*32 + (lane&31)]
//   t in 0..7 (32-col tiles), sc in 0..15 (16-row k-chunks); tile stride 8192.
// Encoder weights keep the 16x16x32 A-frag layout:
//   frag[t][s][lane][j8] = W[(s*32 + (lane>>4)*8 + j)*256 + t*16 + (lane&15)]
#define OFF_W2F  0u
#define OFF_W3F  65536u
#define OFF_WQEF 131072u
#define OFF_WKEF 262144u
#define OFF_WCQ  393216u
#define OFF_WCK  524288u
#define OFF_WV2H 655360u     // 256 f16
#define F16_WS_END_BYTES 1312768u

union U8 { f16x8 v; h2 h[4]; };

// packed RTZ f32x2 -> f16x2 (v_cvt_pkrtz_f16_f32)
__device__ __forceinline__ ushort2 f2h2(float x, float y) {
  fp16v2 r = __builtin_amdgcn_cvt_pkrtz(x, y);
  ushort2 u;
  __builtin_memcpy(&u, &r, 4);
  return u;
}
__device__ __forceinline__ float relu_(float x) { return x > 0.f ? x : 0.f; }
__device__ __forceinline__ float softplus_(float x) {
  return fmaxf(x, 0.f) + log1pf(expf(-fabsf(x)));
}

// ---------------------------------------------------------------------------
// K1: shuffle fp32 weights -> f16 MFMA A-frag order via LDS transpose.
// Blocks: 0-7 W2 | 8-15 W3 (32x32 layout) | 16-31 Wqe | 32-47 Wke |
//         48-55 W1top | 56-63 Wv1top | 64-71 W1bot | 72-79 Wv1bot | 80 Wv2
// ---------------------------------------------------------------------------
__global__ __launch_bounds__(256) void shuffle_weights(
    const float* __restrict__ Wqe, const float* __restrict__ Wke,
    const float* __restrict__ W1,  const float* __restrict__ Wv1,
    const float* __restrict__ W2,  const float* __restrict__ W3,
    const float* __restrict__ Wv2,
    unsigned short* __restrict__ wsb)
{
  __shared__ float sW[32 * 257];   // pad +1: transpose reads conflict-light
  const int bx = blockIdx.x;
  const int t = threadIdx.x;
  if (bx == 80) {
    if (t < 64) {
      float a = Wv2[t * 4 + 0], b = Wv2[t * 4 + 1];
      float c = Wv2[t * 4 + 2], d = Wv2[t * 4 + 3];
      ushort2 lo = f2h2(a, b), hi = f2h2(c, d);
      ushort4 o; o.x = lo.x; o.y = lo.y; o.z = hi.x; o.w = hi.y;
      *(ushort4*)&wsb[OFF_WV2H + t * 4] = o;
    }
    return;
  }
  const float* src; unsigned short* dst; int s; int S;
  if      (bx <  8) { src = W2;          dst = wsb + OFF_W2F;           s = bx;      S = 8;  }
  else if (bx < 16) { src = W3;          dst = wsb + OFF_W3F;           s = bx - 8;  S = 8;  }
  else if (bx < 32) { src = Wqe;         dst = wsb + OFF_WQEF;          s = bx - 16; S = 16; }
  else if (bx < 48) { src = Wke;         dst = wsb + OFF_WKEF;          s = bx - 32; S = 16; }
  else if (bx < 56) { src = W1;          dst = wsb + OFF_WCQ;           s = bx - 48; S = 8;  }
  else if (bx < 64) { src = Wv1;         dst = wsb + OFF_WCQ + 65536u;  s = bx - 56; S = 8;  }
  else if (bx < 72) { src = W1 + 65536;  dst = wsb + OFF_WCK;           s = bx - 64; S = 8;  }
  else              { src = Wv1 + 65536; dst = wsb + OFF_WCK + 65536u;  s = bx - 72; S = 8;  }

  const int kbase = s * 32;
  #pragma unroll
  for (int it = 0; it < 8; ++it) {
    const int f4 = it * 256 + t;
    const int row = f4 >> 6, c4 = (f4 & 63) * 4;
    float4 v = *(const float4*)(src + (size_t)(kbase + row) * 256 + c4);
    sW[row * 257 + c4 + 0] = v.x; sW[row * 257 + c4 + 1] = v.y;
    sW[row * 257 + c4 + 2] = v.z; sW[row * 257 + c4 + 3] = v.w;
  }
  __syncthreads();

  const int wave = t >> 6, lane = t & 63;

  if (bx < 16) {
    // 32x32x16 A-frag layout for W2/W3. This block's 32 k-rows are
    // k-chunks sc = 2s, 2s+1. lane: n_in = lane&31, k-half = (lane>>5)*8.
    const int n_in = lane & 31, kh = (lane >> 5) * 8;
    #pragma unroll
    for (int it = 0; it < 4; ++it) {
      const int tt  = wave * 2 + (it >> 1);   // 0..7 (32-col tile)
      const int scl = it & 1;                 // local k-chunk
      const int k0 = scl * 16 + kh;
      float x[8];
      #pragma unroll
      for (int j = 0; j < 8; ++j) x[j] = sW[(k0 + j) * 257 + tt * 32 + n_in];
      ushort2 p0 = f2h2(x[0], x[1]), p1 = f2h2(x[2], x[3]);
      ushort2 p2 = f2h2(x[4], x[5]), p3 = f2h2(x[6], x[7]);
      ushort4 lo; lo.x = p0.x; lo.y = p0.y; lo.z = p1.x; lo.w = p1.y;
      ushort4 hi; hi.x = p2.x; hi.y = p2.y; hi.z = p3.x; hi.w = p3.y;
      unsigned short* o = dst + ((size_t)(tt * 16 + (s * 2 + scl)) * 64 + lane) * 8;
      *(ushort4*)&o[0] = lo; *(ushort4*)&o[4] = hi;
    }
    return;
  }

  const int n_in = lane & 15, k0 = (lane >> 4) * 8;
  for (int tt = wave * 4; tt < wave * 4 + 4; ++tt) {
    const int n = tt * 16 + n_in;
    float x[8];
    #pragma unroll
    for (int j = 0; j < 8; ++j) x[j] = sW[(k0 + j) * 257 + n];
    ushort2 p0 = f2h2(x[0], x[1]), p1 = f2h2(x[2], x[3]);
    ushort2 p2 = f2h2(x[4], x[5]), p3 = f2h2(x[6], x[7]);
    ushort4 lo; lo.x = p0.x; lo.y = p0.y; lo.z = p1.x; lo.w = p1.y;
    ushort4 hi; hi.x = p2.x; hi.y = p2.y; hi.z = p3.x; hi.w = p3.y;
    unsigned short* o = dst + ((size_t)(tt * S + s) * 64 + lane) * 8;
    *(ushort4*)&o[0] = lo; *(ushort4*)&o[4] = hi;
  }
}

// ---------------------------------------------------------------------------
// K2: encoder + projections (16x16x32 f16 MFMA). Unchanged.
// ---------------------------------------------------------------------------
__global__ __launch_bounds__(512) void encoder_kernel(
    const float* __restrict__ query, const float* __restrict__ key,
    const float* __restrict__ bqe,   const float* __restrict__ bke,
    const float* __restrict__ b1,    const float* __restrict__ bv1,
    const unsigned short* __restrict__ WqeF, const unsigned short* __restrict__ WkeF,
    const unsigned short* __restrict__ WcqF, const unsigned short* __restrict__ WckF,
    _Float16* __restrict__ Pq, _Float16* __restrict__ Pk)
{
  __shared__ unsigned short sX[16 * 520];
  __shared__ unsigned short sF[16 * 264];
  __shared__ float sBe[256];
  __shared__ float sBc[512];

  const int bx   = blockIdx.x;
  const int side = bx >> 8;          // 0 = q, 1 = k
  const int idx  = bx & 255;
  const int rt   = idx >> 2;         // 0..63, 16-row group
  const int nh   = idx & 3;          // 0..3, GEMM2e n-quarter
  const int t    = threadIdx.x;

  const float* Xsrc = side ? key : query;
  const unsigned short* WeF = side ? WkeF : WqeF;
  const unsigned short* WcF = side ? WckF : WcqF;
  _Float16* P = side ? Pk : Pq;

  const int wave = t >> 6, lane = t & 63;
  const int l15 = lane & 15, q4 = lane >> 4;

  // GEMM1e A s=0 prefetch (independent of staging). Tile stride 8192.
  const unsigned short* aeb = WeF + ((size_t)(wave * 2) * 16 * 64 + lane) * 8;
  f16x8 afe[2][2];
  #pragma unroll
  for (int ft = 0; ft < 2; ++ft)
    afe[0][ft] = *(const f16x8*)(aeb + ft * 8192);

  // staging: 16 rows x 512 cols, j-interleaved for full coalescing
  {
    const int m = t >> 5, ch = t & 31;
    const float* xr = Xsrc + (size_t)(rt * 16 + m) * EDIM;
    #pragma unroll
    for (int j = 0; j < 4; ++j) {
      const int c = j * 128 + ch * 4;
      float4 v = *(const float4*)(xr + c);
      ushort2 lo = f2h2(v.x, v.y), hi = f2h2(v.z, v.w);
      ushort4 xb; xb.x = lo.x; xb.y = lo.y; xb.z = hi.x; xb.w = hi.y;
      *(ushort4*)&sX[m * 520 + c] = xb;
    }
    if (t < 256) {
      sBe[t]       = side ? bke[t] : bqe[t];
      sBc[t]       = side ? 0.f : b1[t];
      sBc[256 + t] = side ? 0.f : bv1[t];
    }
  }
  __syncthreads();

  // GEMM1e: D[n][m] = sum_k We[k][n] * X[m][k], K=512 (16 s), 2 tiles/wave
  f32x4 acc1[2];
  #pragma unroll
  for (int ft = 0; ft < 2; ++ft) acc1[ft] = (f32x4){0.f, 0.f, 0.f, 0.f};

  #pragma unroll
  for (int s = 0; s < 16; ++s) {
    if (s < 15) {
      #pragma unroll
      for (int ft = 0; ft < 2; ++ft)
        afe[(s + 1) & 1][ft] = *(const f16x8*)(aeb + ft * 8192 + (size_t)(s + 1) * 512);
    }
    f16x8 bfr = *(const f16x8*)&sX[l15 * 520 + s * 32 + q4 * 8];
    #pragma unroll
    for (int ft = 0; ft < 2; ++ft)
      acc1[ft] = __builtin_amdgcn_mfma_f32_16x16x32_f16(afe[s & 1][ft], bfr, acc1[ft], 0, 0, 0);
  }

  // Epilogue 1: F = relu(D + be) -> f16 LDS [m][n]
  #pragma unroll
  for (int ft = 0; ft < 2; ++ft) {
    const int tg = wave * 2 + ft;
    const int n0 = tg * 16 + q4 * 4;
    float4 b4 = *(const float4*)&sBe[n0];
    f32x4 a = acc1[ft];
    ushort2 lo = f2h2(relu_(a[0] + b4.x), relu_(a[1] + b4.y));
    ushort2 hi = f2h2(relu_(a[2] + b4.z), relu_(a[3] + b4.w));
    ushort4 h; h.x = lo.x; h.y = lo.y; h.z = hi.x; h.w = hi.y;
    *(ushort4*)&sF[l15 * 264 + n0] = h;
  }
  __syncthreads();

  // GEMM2e: this block's quarter: tg = nh*8 + wave, 1 tile/wave, K=256 (8 s)
  const int tg2 = nh * 8 + wave;
  const unsigned short* acb = WcF + ((size_t)tg2 * 8 * 64 + lane) * 8;
  f16x8 afc[2];
  afc[0] = *(const f16x8*)(acb);

  f32x4 acc2 = (f32x4){0.f, 0.f, 0.f, 0.f};

  #pragma unroll
  for (int s = 0; s < 8; ++s) {
    if (s < 7)
      afc[(s + 1) & 1] = *(const f16x8*)(acb + (size_t)(s + 1) * 512);
    f16x8 bfr = *(const f16x8*)&sF[l15 * 264 + s * 32 + q4 * 8];
    acc2 = __builtin_amdgcn_mfma_f32_16x16x32_f16(afc[s & 1], bfr, acc2, 0, 0, 0);
  }

  // Epilogue 2: store P[row][n] = f16(D + bias)
  {
    const int n0 = tg2 * 16 + q4 * 4;
    float4 bc = *(const float4*)&sBc[n0];
    const int row = rt * 16 + l15;
    ushort2 lo = f2h2(acc2[0] + bc.x, acc2[1] + bc.y);
    ushort2 hi = f2h2(acc2[2] + bc.z, acc2[3] + bc.w);
    ushort4 o; o.x = lo.x; o.y = lo.y; o.z = hi.x; o.w = hi.y;
    *(ushort4*)((unsigned short*)P + (size_t)row * 512 + n0) = o;
  }
}

// ---------------------------------------------------------------------------
// K3: fused pair kernel — R21: 32x32x16 MFMA (issue-count attack).
// Ledger R0-R6: barriers/setprio/bias/A-depth(1->3)/LDS-traffic/occupancy
// all null or negative; A-depth 1->0 = -31% (R6). R0 shows MfmaUtil 37 +
// VALUBusy 44.5 = 81% combined issue-busy -> near issue-bound. This round
// halves MFMA instr count (64->32 per wave per GEMM, 2x FLOP each, ~15%
// better pipe efficiency) and cuts GEMM-phase instrs 112->80 per wave.
// 8 waves = 2 m-tiles(32) x 4 n-groups x 2 n-tiles(32); acc = 2 f32x16 =
// 32 regs (same as R0). A prefetch depth 1 (proven sufficient); B depth 2
// (LDS ~120cy vs ~60cy 1-step lookahead was the identified residual gap).
// A-frags shared by the 2 mi-waves -> L1 hit (R6: FETCH stayed 5.7MB).
// ---------------------------------------------------------------------------
__global__ __launch_bounds__(512, 4) void pair_kernel(
    const _Float16* __restrict__ Pq, const _Float16* __restrict__ Pk,
    const unsigned short* __restrict__ W2F, const unsigned short* __restrict__ W3F,
    const float* __restrict__ b2, const float* __restrict__ b3,
    const float* __restrict__ Wf, const float* __restrict__ bfp,
    const unsigned short* __restrict__ Wv2H, const float* __restrict__ bv2p,
    float* __restrict__ out)
{
  __shared__ __align__(16) unsigned char smem[68608];
  unsigned short* sXH = (unsigned short*)smem;           // 64*264 f16 = 33792 B
  unsigned short* sH  = (unsigned short*)(smem + 33792); // 64*264 f16 = 33792 B
  float* sRed = (float*)(smem + 67584);                  // 4*64*4 = 1024 B

  const int kt = blockIdx.x, qy = blockIdx.y, bz = blockIdx.z;
  const int t = threadIdx.x;
  const _Float16* qpRow = Pq + (size_t)(bz * NSQ + qy) * 512;

  const int wave = t >> 6, lane = t & 63;
  const int l31 = lane & 31, kh = lane >> 5;   // kh: k-half 0/1
  const int mi = wave >> 2;                    // m-tile (32 rows)
  const int nj = wave & 3;                     // n-group (2 x 32-col tiles)

  // A-frag bases: tiles nj*2, nj*2+1; tile stride 8192, sc-stride 512.
  const unsigned short* a2b = W2F + (size_t)(nj * 2) * 8192 + lane * 8;
  const unsigned short* a3b = W3F + (size_t)(nj * 2) * 8192 + lane * 8;

  // GEMM1 sc=0 A prefetch before staging.
  f16x8 a0c = *(const f16x8*)(a2b);
  f16x8 a1c = *(const f16x8*)(a2b + 8192);

  // --- staging: X1 = relu(qp+kp) (packed f16, pad-264) + variance fdot2 ---
  float vp0 = 0.f, vp1 = 0.f;
  {
    const int m   = t >> 3;     // 0..63 pair row
    const int sub = t & 7;      // 0..7
    const _Float16* kpRow = Pk + (size_t)(bz * NSK + kt * 64 + m) * 512;
    const f16x8 z8 = {0, 0, 0, 0, 0, 0, 0, 0};
    #pragma unroll
    for (int it = 0; it < 4; ++it) {
      const int c = it * 64 + sub * 8;
      f16x8 q8 = *(const f16x8*)(qpRow + c);
      f16x8 k8 = *(const f16x8*)(kpRow + c);
      f16x8 r  = __builtin_elementwise_max(q8 + k8, z8);
      *(f16x8*)&sXH[m * 264 + c] = r;
      f16x8 a8 = *(const f16x8*)(qpRow + 256 + c);
      f16x8 v8 = *(const f16x8*)(kpRow + 256 + c);
      U8 ar; ar.v = __builtin_elementwise_max(a8 + v8, z8);
      U8 w8; w8.v = *(const f16x8*)((const _Float16*)Wv2H + c);
      vp0 = __builtin_amdgcn_fdot2(ar.h[0], w8.h[0], vp0, false);
      vp1 = __builtin_amdgcn_fdot2(ar.h[1], w8.h[1], vp1, false);
      vp0 = __builtin_amdgcn_fdot2(ar.h[2], w8.h[2], vp0, false);
      vp1 = __builtin_amdgcn_fdot2(ar.h[3], w8.h[3], vp1, false);
    }
  }
  __syncthreads();

  const int m = mi * 32 + l31;             // this lane's pair row
  const int brow = m * 264 + kh * 8;       // B-frag base (+ sc*16)

  // --- GEMM1: D1[n][m] = sum_k W2[k][n] * X1[m][k], 16 sc-steps ---
  f32x16 acc0, acc1;
  #pragma unroll
  for (int i = 0; i < 16; ++i) { acc0[i] = 0.f; acc1[i] = 0.f; }

  f16x8 bc = *(const f16x8*)&sXH[brow];
  f16x8 b1f = *(const f16x8*)&sXH[brow + 16];

  #pragma unroll
  for (int sc = 0; sc < 16; ++sc) {
    f16x8 a0n, a1n, b2n;
    if (sc < 15) {
      a0n = *(const f16x8*)(a2b + (size_t)(sc + 1) * 512);
      a1n = *(const f16x8*)(a2b + 8192 + (size_t)(sc + 1) * 512);
    }
    if (sc < 14)
      b2n = *(const f16x8*)&sXH[brow + (sc + 2) * 16];
    __builtin_amdgcn_s_setprio(1);
    acc0 = __builtin_amdgcn_mfma_f32_32x32x16_f16(a0c, bc, acc0, 0, 0, 0);
    acc1 = __builtin_amdgcn_mfma_f32_32x32x16_f16(a1c, bc, acc1, 0, 0, 0);
    __builtin_amdgcn_s_setprio(0);
    a0c = a0n; a1c = a1n; bc = b1f; b1f = b2n;
  }
  // No barrier: epilogue 1 writes the separate sH buffer.

  // GEMM2 sc=0 A prefetch in the epilogue shadow.
  a0c = *(const f16x8*)(a3b);
  a1c = *(const f16x8*)(a3b + 8192);

  // --- Epilogue 1: H1 = relu(D1 + b2) -> sH (pad-264) ---
  // C/D: col(lane&31)=m, row = (reg&3) + 8*(reg>>2) + 4*kh = n within tile.
  #pragma unroll
  for (int ti = 0; ti < 2; ++ti) {
    const f32x16 a = ti ? acc1 : acc0;
    const int nb = (nj * 2 + ti) * 32 + kh * 4;
    #pragma unroll
    for (int g = 0; g < 4; ++g) {
      const int n0 = nb + g * 8;
      float4 b4 = *(const float4*)&b2[n0];
      ushort2 lo = f2h2(relu_(a[g * 4 + 0] + b4.x), relu_(a[g * 4 + 1] + b4.y));
      ushort2 hi = f2h2(relu_(a[g * 4 + 2] + b4.z), relu_(a[g * 4 + 3] + b4.w));
      ushort4 h; h.x = lo.x; h.y = lo.y; h.z = hi.x; h.w = hi.y;
      *(ushort4*)&sH[m * 264 + n0] = h;
    }
  }
  __syncthreads();   // H1 visible before GEMM2 reads

  // --- GEMM2: D2[n][m] = sum_k W3[k][n] * H1[m][k] ---
  #pragma unroll
  for (int i = 0; i < 16; ++i) { acc0[i] = 0.f; acc1[i] = 0.f; }

  bc  = *(const f16x8*)&sH[brow];
  b1f = *(const f16x8*)&sH[brow + 16];

  #pragma unroll
  for (int sc = 0; sc < 16; ++sc) {
    f16x8 a0n, a1n, b2n;
    if (sc < 15) {
      a0n = *(const f16x8*)(a3b + (size_t)(sc + 1) * 512);
      a1n = *(const f16x8*)(a3b + 8192 + (size_t)(sc + 1) * 512);
    }
    if (sc < 14)
      b2n = *(const f16x8*)&sH[brow + (sc + 2) * 16];
    __builtin_amdgcn_s_setprio(1);
    acc0 = __builtin_amdgcn_mfma_f32_32x32x16_f16(a0c, bc, acc0, 0, 0, 0);
    acc1 = __builtin_amdgcn_mfma_f32_32x32x16_f16(a1c, bc, acc1, 0, 0, 0);
    __builtin_amdgcn_s_setprio(0);
    a0c = a0n; a1c = a1n; bc = b1f; b1f = b2n;
  }

  // --- variance head: reduce + store (off the staging critical path) ---
  {
    float v = vp0 + vp1;
    v += __shfl_xor(v, 1, 64);
    v += __shfl_xor(v, 2, 64);
    v += __shfl_xor(v, 4, 64);
    if ((t & 7) == 0) {
      const int mr = t >> 3;
      const size_t o = (size_t)(bz * NSQ + qy) * NSK + kt * 64 + mr;
      out[(size_t)NB * NSQ * NSK + o] = softplus_(v + bv2p[0]);
    }
  }

  // --- Final epilogue: logit partial over this wave's 64 n-cols ---
  {
    float p = 0.f;
    #pragma unroll
    for (int ti = 0; ti < 2; ++ti) {
      const f32x16 a = ti ? acc1 : acc0;
      const int nb = (nj * 2 + ti) * 32 + kh * 4;
      #pragma unroll
      for (int g = 0; g < 4; ++g) {
        const int n0 = nb + g * 8;
        float4 b4 = *(const float4*)&b3[n0];
        float4 w4 = *(const float4*)&Wf[n0];
        p += relu_(a[g * 4 + 0] + b4.x) * w4.x + relu_(a[g * 4 + 1] + b4.y) * w4.y
           + relu_(a[g * 4 + 2] + b4.z) * w4.z + relu_(a[g * 4 + 3] + b4.w) * w4.w;
      }
    }
    // lanes l and l+32 hold same m, disjoint n-halves: one xor folds them.
    p += __shfl_xor(p, 32, 64);
    if (lane < 32) sRed[nj * 64 + m] = p;
  }
  __syncthreads();

  if (t < 64) {
    const size_t o = (size_t)(bz * NSQ + qy) * NSK + kt * 64 + t;
    float lg = bfp[0];
    #pragma unroll
    for (int w = 0; w < 4; ++w) lg += sRed[w * 64 + t];
    out[o] = lg;
  }
}

// ---------------------------------------------------------------------------
extern "C" void kernel_launch(void* const* d_in, const int* in_sizes, int n_in,
                              void* d_out, int out_size, void* d_ws, size_t ws_size,
                              hipStream_t stream)
{
  (void)in_sizes; (void)n_in; (void)out_size; (void)ws_size;
  const float* query = (const float*)d_in[0];
  const float* key   = (const float*)d_in[1];
  const float* Wqe   = (const float*)d_in[2];
  const float* bqe   = (const float*)d_in[3];
  const float* Wke   = (const float*)d_in[4];
  const float* bke   = (const float*)d_in[5];
  const float* W1    = (const float*)d_in[6];
  const float* b1    = (const float*)d_in[7];
  const float* W2    = (const float*)d_in[8];
  const float* b2    = (const float*)d_in[9];
  const float* W3    = (const float*)d_in[10];
  const float* b3    = (const float*)d_in[11];
  const float* Wf    = (const float*)d_in[12];
  const float* bf    = (const float*)d_in[13];
  const float* Wv1   = (const float*)d_in[14];
  const float* bv1   = (const float*)d_in[15];
  const float* Wv2   = (const float*)d_in[16];
  const float* bv2   = (const float*)d_in[17];

  unsigned short* wsb = (unsigned short*)d_ws;
  _Float16* Pq = (_Float16*)((char*)d_ws + F16_WS_END_BYTES);   // [1024][512] f16
  _Float16* Pk = Pq + (size_t)1024 * 512;                       // [1024][512] f16
  float* out = (float*)d_out;

  shuffle_weights<<<81, 256, 0, stream>>>(Wqe, Wke, W1, Wv1, W2, W3, Wv2, wsb);
  encoder_kernel<<<512, 512, 0, stream>>>(query, key, bqe, bke, b1, bv1,
      wsb + OFF_WQEF, wsb + OFF_WKEF, wsb + OFF_WCQ, wsb + OFF_WCK, Pq, Pk);
  pair_kernel<<<dim3(NSK / 64, NSQ, NB), 512, 0, stream>>>(Pq, Pk,
      wsb + OFF_W2F, wsb + OFF_W3F, b2, b3, Wf, bf, wsb + OFF_WV2H, bv2, out);
}